// Round 7
// baseline (230.838 us; speedup 1.0000x reference)
//
#include <hip/hip_runtime.h>
#include <hip/hip_bf16.h>

// Deformable 3D conv: B=2, CIN=COUT=64, D=8,H=32,W=32, K=27, stride=1,pad=1,dil=1
// Round 7: register-only pipeline. Lane = (position n0=lane&15, chan-chunk q=lane>>4),
// so sampled values land directly in MFMA B-frag layout: no LDS, no barriers, no
// cross-lane traffic at all. Each lane computes its own position's coords (x4
// redundant across q - cheaper than communication). K split 9 ways (3 k/block).

#define BB    2
#define CINC  64
#define COUTC 64
#define DDEP  8
#define HGT   32
#define WID   32
#define KK    27
#define KGRP  9
#define KPB   3         // k's per block
#define PP    8192      // DOUT*HOUT*WOUT
#define TPW   16        // positions per (1-wave) block

typedef short s16x8 __attribute__((ext_vector_type(8)));
typedef float f32x4 __attribute__((ext_vector_type(4)));
typedef float f32x2 __attribute__((ext_vector_type(2)));

__device__ __forceinline__ unsigned short f2bf(float f) {
    unsigned u = __builtin_bit_cast(unsigned, f);
    u += 0x7FFFu + ((u >> 16) & 1u);   // RNE
    return (unsigned short)(u >> 16);
}

__device__ __forceinline__ unsigned pack2bf(float lo, float hi) {
    return (unsigned)f2bf(lo) | ((unsigned)f2bf(hi) << 16);
}

__device__ __forceinline__ f32x2 bfu2(unsigned v) {
    f32x2 r;
    r.x = __builtin_bit_cast(float, v << 16);
    r.y = __builtin_bit_cast(float, v & 0xFFFF0000u);
    return r;
}

// Fused pre-kernel:
//  blocks [0,256): transpose+convert x[b][c][s] fp32 -> xt[b][s][c] bf16
//  blocks [256,688): weight (COUT,CIN,27) fp32 -> wt[(k*64+o)*64+c] bf16
__global__ void pre_kernel(const float* __restrict__ x, const float* __restrict__ w,
                           unsigned short* __restrict__ xt, unsigned short* __restrict__ wt) {
    __shared__ float sT[64][65];
    const int t    = threadIdx.x;
    const int lane = t & 63;
    const int wv   = t >> 6;
    const int half = lane >> 5;
    const int c2   = lane & 31;
    int blk = blockIdx.x;
    if (blk < 256) {
        int b  = blk >> 7;
        int s0 = (blk & 127) * 64;
        #pragma unroll
        for (int i = 0; i < 16; ++i) {
            int c = wv * 16 + i;
            sT[c][lane] = x[(size_t)(b * CINC + c) * PP + s0 + lane];
        }
        __syncthreads();
        #pragma unroll
        for (int i = 0; i < 8; ++i) {
            int s = wv * 16 + 2 * i + half;
            unsigned pk = pack2bf(sT[2 * c2][s], sT[2 * c2 + 1][s]);
            *(unsigned*)&xt[(size_t)(b * PP + s0 + s) * 64 + 2 * c2] = pk;
        }
    } else {
        int id = (blk - 256) * 256 + t;
        if (id < KK * COUTC * CINC) {
            int c = id & 63;
            int o = (id >> 6) & 63;
            int k = id >> 12;
            wt[id] = f2bf(w[(o * CINC + c) * KK + k]);
        }
    }
}

__device__ __forceinline__ void acc4pk(f32x2* s2, int4 v, float wg) {
    f32x2 wg2; wg2.x = wg; wg2.y = wg;
    s2[0] += wg2 * bfu2((unsigned)v.x);
    s2[1] += wg2 * bfu2((unsigned)v.y);
    s2[2] += wg2 * bfu2((unsigned)v.z);
    s2[3] += wg2 * bfu2((unsigned)v.w);
}

__global__ __launch_bounds__(64, 6) void deform_kernel(
    const unsigned short* __restrict__ xt, const float* __restrict__ off,
    const unsigned short* __restrict__ wt, const float* __restrict__ bias,
    float* __restrict__ out)
{
    const int lane = threadIdx.x;          // one wave per block
    const int n0   = lane & 15;            // my position within tile
    const int q    = lane >> 4;            // my channel chunk (8q..8q+7, +32 for step1)
    const int b    = blockIdx.x >> 9;      // 512 tiles per batch
    const int p0   = (blockIdx.x & 511) * TPW;
    const int kg   = blockIdx.y;           // 0..8

    const int pp = p0 + n0;
    const int ow = pp & 31;
    const int oh = (pp >> 5) & 31;
    const int od = pp >> 10;

    // byte base for my channel chunk: xt elem (b*PP + voxel)*64 + 8q -> bytes
    const char* xbq = (const char*)xt + (size_t)b * PP * 128 + q * 16;

    f32x4 acc[4];
    #pragma unroll
    for (int f = 0; f < 4; ++f) acc[f] = (f32x4)0.0f;

    #pragma unroll
    for (int kl = 0; kl < KPB; ++kl) {
        const int k  = kg * KPB + kl;
        const int kd = k / 9;
        const int kh = (k - kd * 9) / 3;
        const int kw = k - kd * 9 - kh * 3;

        // ---- my position's coords for this k (no cross-lane communication)
        const float* ob = off + (size_t)(b * (3 * KK) + 3 * k) * PP + pp;
        float zd = (float)(od - 1 + kd) + ob[0];
        float zh = (float)(oh - 1 + kh) + ob[PP];
        float zw = (float)(ow - 1 + kw) + ob[2 * PP];

        float fdf = floorf(zd); int d0 = (int)fdf; float fd = zd - fdf;
        float fhf = floorf(zh); int h0 = (int)fhf; float fh = zh - fhf;
        float fwf = floorf(zw); int w0 = (int)fwf; float fw = zw - fwf;

        float Bd0 = (d0 >= 0     && d0 < DDEP)     ? 1.0f - fd : 0.0f;
        float Bd1 = (d0 + 1 >= 0 && d0 + 1 < DDEP) ? fd        : 0.0f;
        float Ch0 = (h0 >= 0     && h0 < HGT)      ? 1.0f - fh : 0.0f;
        float Ch1 = (h0 + 1 >= 0 && h0 + 1 < HGT)  ? fh        : 0.0f;
        float Aw0 = (w0 >= 0     && w0 < WID)      ? 1.0f - fw : 0.0f;
        float Aw1 = (w0 + 1 >= 0 && w0 + 1 < WID)  ? fw        : 0.0f;
        int dc0 = min(max(d0, 0), DDEP - 1);
        int dc1 = min(max(d0 + 1, 0), DDEP - 1);
        int hc0 = min(max(h0, 0), HGT - 1);
        int hc1 = min(max(h0 + 1, 0), HGT - 1);
        int wc0 = min(max(w0, 0), WID - 1);
        int wc1 = min(max(w0 + 1, 0), WID - 1);

        int dh0 = (dc0 * HGT + hc0) * WID;
        int dh1 = (dc0 * HGT + hc1) * WID;
        int dh2 = (dc1 * HGT + hc0) * WID;
        int dh3 = (dc1 * HGT + hc1) * WID;
        // byte offsets (voxel * 128)
        int vo[8];
        vo[0] = (dh0 + wc0) << 7;
        vo[1] = (dh1 + wc0) << 7;
        vo[2] = (dh2 + wc0) << 7;
        vo[3] = (dh3 + wc0) << 7;
        vo[4] = (dh0 + wc1) << 7;
        vo[5] = (dh1 + wc1) << 7;
        vo[6] = (dh2 + wc1) << 7;
        vo[7] = (dh3 + wc1) << 7;
        float bc0 = Bd0 * Ch0, bc1 = Bd0 * Ch1, bc2 = Bd1 * Ch0, bc3 = Bd1 * Ch1;
        float wg[8];
        wg[0] = bc0 * Aw0; wg[1] = bc1 * Aw0; wg[2] = bc2 * Aw0; wg[3] = bc3 * Aw0;
        wg[4] = bc0 * Aw1; wg[5] = bc1 * Aw1; wg[6] = bc2 * Aw1; wg[7] = bc3 * Aw1;

        // ---- gather + accumulate; s2[0..3]=channels 8q.., s2[4..7]=channels 32+8q..
        f32x2 s2[8];
        #pragma unroll
        for (int j = 0; j < 8; ++j) { s2[j].x = 0.0f; s2[j].y = 0.0f; }

        int4 va[8];
        #pragma unroll
        for (int c = 0; c < 8; ++c) va[c] = *(const int4*)(xbq + vo[c]);
        #pragma unroll
        for (int c = 0; c < 8; ++c) acc4pk(&s2[0], va[c], wg[c]);
        #pragma unroll
        for (int c = 0; c < 8; ++c) va[c] = *(const int4*)(xbq + vo[c] + 64);
        #pragma unroll
        for (int c = 0; c < 8; ++c) acc4pk(&s2[4], va[c], wg[c]);

        // ---- pack to B-frags (already in MFMA B layout: k=8q+j, n=n0)
        s16x8 b0, b1;
        {
            int4 pk0, pk1;
            pk0.x = (int)pack2bf(s2[0].x, s2[0].y);
            pk0.y = (int)pack2bf(s2[1].x, s2[1].y);
            pk0.z = (int)pack2bf(s2[2].x, s2[2].y);
            pk0.w = (int)pack2bf(s2[3].x, s2[3].y);
            pk1.x = (int)pack2bf(s2[4].x, s2[4].y);
            pk1.y = (int)pack2bf(s2[5].x, s2[5].y);
            pk1.z = (int)pack2bf(s2[6].x, s2[6].y);
            pk1.w = (int)pack2bf(s2[7].x, s2[7].y);
            b0 = __builtin_bit_cast(s16x8, pk0);
            b1 = __builtin_bit_cast(s16x8, pk1);
        }

        // ---- MFMA with weight A-frags straight from global (L2-hot)
        const unsigned short* wk = wt + k * (COUTC * CINC) + n0 * 64 + 8 * q;
        #pragma unroll
        for (int f = 0; f < 4; ++f) {
            s16x8 a0 = *(const s16x8*)(wk + f * 1024);
            s16x8 a1 = *(const s16x8*)(wk + f * 1024 + 32);
            acc[f] = __builtin_amdgcn_mfma_f32_16x16x32_bf16(a0, b0, acc[f], 0, 0, 0);
            acc[f] = __builtin_amdgcn_mfma_f32_16x16x32_bf16(a1, b1, acc[f], 0, 0, 0);
        }
    }

    // ---- epilogue: atomic partial accumulate; bias added by kg==0.
    // C/D layout: col=lane&15 -> p = p0+n0 ; row=4q+r -> o = 16f+4q+r
    const int pdst = p0 + n0;
    #pragma unroll
    for (int f = 0; f < 4; ++f) {
        #pragma unroll
        for (int r = 0; r < 4; ++r) {
            int o = 16 * f + 4 * q + r;
            float add = acc[f][r] + ((kg == 0) ? bias[o] : 0.0f);
            unsafeAtomicAdd(&out[(size_t)(b * COUTC + o) * PP + pdst], add);
        }
    }
}

extern "C" void kernel_launch(void* const* d_in, const int* in_sizes, int n_in,
                              void* d_out, int out_size, void* d_ws, size_t ws_size,
                              hipStream_t stream) {
    const float* x    = (const float*)d_in[0];
    const float* off  = (const float*)d_in[1];
    const float* w    = (const float*)d_in[2];
    const float* bias = (const float*)d_in[3];
    float* out        = (float*)d_out;

    unsigned short* xt = (unsigned short*)d_ws;                       // 2*8192*64*2 = 2 MB
    unsigned short* wt = (unsigned short*)((char*)d_ws + (size_t)BB * PP * 64 * 2); // 221184 B

    (void)hipMemsetAsync(out, 0, (size_t)out_size * sizeof(float), stream);
    hipLaunchKernelGGL(pre_kernel, dim3(256 + (KK * COUTC * CINC + 255) / 256), dim3(256), 0,
                       stream, x, w, xt, wt);
    hipLaunchKernelGGL(deform_kernel, dim3(BB * (PP / TPW), KGRP), dim3(64), 0, stream,
                       xt, off, wt, bias, out);
}

// Round 8
// 153.497 us; speedup vs baseline: 1.5039x; 1.5039x over previous
//
#include <hip/hip_runtime.h>
#include <hip/hip_bf16.h>

// Deformable 3D conv: B=2, CIN=COUT=64, D=8,H=32,W=32, K=27, stride=1,pad=1,dil=1
// Round 8: register-direct B-frag pipeline (no LDS, no barriers) + NO ATOMICS.
// deform stores per-kg partials (plain coalesced stores) to d_ws; reduce_kernel
// sums 9 partials + bias. launch_bounds(64,3) gives ~170 VGPR so the dual 8-load
// gather batches (16 in flight) + next-k coord prefetch actually pipeline.

#define BB    2
#define CINC  64
#define COUTC 64
#define DDEP  8
#define HGT   32
#define WID   32
#define KK    27
#define KGRP  9
#define KPB   3         // k's per block
#define PP    8192      // DOUT*HOUT*WOUT
#define TPW   16        // positions per (1-wave) block
#define OUTSZ (BB * COUTC * PP)          // 1048576 elements
#define XT_BYTES  ((size_t)BB * PP * 64 * 2)        // 2097152
#define WT_BYTES  ((size_t)KK * COUTC * CINC * 2)   // 221184

typedef short s16x8 __attribute__((ext_vector_type(8)));
typedef float f32x4 __attribute__((ext_vector_type(4)));
typedef float f32x2 __attribute__((ext_vector_type(2)));

__device__ __forceinline__ unsigned short f2bf(float f) {
    unsigned u = __builtin_bit_cast(unsigned, f);
    u += 0x7FFFu + ((u >> 16) & 1u);   // RNE
    return (unsigned short)(u >> 16);
}

__device__ __forceinline__ unsigned pack2bf(float lo, float hi) {
    return (unsigned)f2bf(lo) | ((unsigned)f2bf(hi) << 16);
}

__device__ __forceinline__ f32x2 bfu2(unsigned v) {
    f32x2 r;
    r.x = __builtin_bit_cast(float, v << 16);
    r.y = __builtin_bit_cast(float, v & 0xFFFF0000u);
    return r;
}

// Fused pre-kernel:
//  blocks [0,256): transpose+convert x[b][c][s] fp32 -> xt[b][s][c] bf16
//  blocks [256,688): weight (COUT,CIN,27) fp32 -> wt[(k*64+o)*64+c] bf16
__global__ void pre_kernel(const float* __restrict__ x, const float* __restrict__ w,
                           unsigned short* __restrict__ xt, unsigned short* __restrict__ wt) {
    __shared__ float sT[64][65];
    const int t    = threadIdx.x;
    const int lane = t & 63;
    const int wv   = t >> 6;
    const int half = lane >> 5;
    const int c2   = lane & 31;
    int blk = blockIdx.x;
    if (blk < 256) {
        int b  = blk >> 7;
        int s0 = (blk & 127) * 64;
        #pragma unroll
        for (int i = 0; i < 16; ++i) {
            int c = wv * 16 + i;
            sT[c][lane] = x[(size_t)(b * CINC + c) * PP + s0 + lane];
        }
        __syncthreads();
        #pragma unroll
        for (int i = 0; i < 8; ++i) {
            int s = wv * 16 + 2 * i + half;
            unsigned pk = pack2bf(sT[2 * c2][s], sT[2 * c2 + 1][s]);
            *(unsigned*)&xt[(size_t)(b * PP + s0 + s) * 64 + 2 * c2] = pk;
        }
    } else {
        int id = (blk - 256) * 256 + t;
        if (id < KK * COUTC * CINC) {
            int c = id & 63;
            int o = (id >> 6) & 63;
            int k = id >> 12;
            wt[id] = f2bf(w[(o * CINC + c) * KK + k]);
        }
    }
}

__device__ __forceinline__ void acc4pk(f32x2* s2, int4 v, float wg) {
    f32x2 wg2; wg2.x = wg; wg2.y = wg;
    s2[0] += wg2 * bfu2((unsigned)v.x);
    s2[1] += wg2 * bfu2((unsigned)v.y);
    s2[2] += wg2 * bfu2((unsigned)v.z);
    s2[3] += wg2 * bfu2((unsigned)v.w);
}

// per-lane coords for kernel tap k at position pp: 8 corner byte-offsets + weights
__device__ __forceinline__ void coords_k(const float* __restrict__ off, int b, int k,
                                         int pp, int ow, int oh, int od,
                                         int* __restrict__ vo, float* __restrict__ wg)
{
    const int kd = k / 9;
    const int kh = (k - kd * 9) / 3;
    const int kw = k - kd * 9 - kh * 3;
    const float* ob = off + (size_t)(b * (3 * KK) + 3 * k) * PP + pp;
    float zd = (float)(od - 1 + kd) + ob[0];
    float zh = (float)(oh - 1 + kh) + ob[PP];
    float zw = (float)(ow - 1 + kw) + ob[2 * PP];

    float fdf = floorf(zd); int d0 = (int)fdf; float fd = zd - fdf;
    float fhf = floorf(zh); int h0 = (int)fhf; float fh = zh - fhf;
    float fwf = floorf(zw); int w0 = (int)fwf; float fw = zw - fwf;

    float Bd0 = (d0 >= 0     && d0 < DDEP)     ? 1.0f - fd : 0.0f;
    float Bd1 = (d0 + 1 >= 0 && d0 + 1 < DDEP) ? fd        : 0.0f;
    float Ch0 = (h0 >= 0     && h0 < HGT)      ? 1.0f - fh : 0.0f;
    float Ch1 = (h0 + 1 >= 0 && h0 + 1 < HGT)  ? fh        : 0.0f;
    float Aw0 = (w0 >= 0     && w0 < WID)      ? 1.0f - fw : 0.0f;
    float Aw1 = (w0 + 1 >= 0 && w0 + 1 < WID)  ? fw        : 0.0f;
    int dc0 = min(max(d0, 0), DDEP - 1);
    int dc1 = min(max(d0 + 1, 0), DDEP - 1);
    int hc0 = min(max(h0, 0), HGT - 1);
    int hc1 = min(max(h0 + 1, 0), HGT - 1);
    int wc0 = min(max(w0, 0), WID - 1);
    int wc1 = min(max(w0 + 1, 0), WID - 1);

    int dh0 = (dc0 * HGT + hc0) * WID;
    int dh1 = (dc0 * HGT + hc1) * WID;
    int dh2 = (dc1 * HGT + hc0) * WID;
    int dh3 = (dc1 * HGT + hc1) * WID;
    vo[0] = (dh0 + wc0) << 7;
    vo[1] = (dh1 + wc0) << 7;
    vo[2] = (dh2 + wc0) << 7;
    vo[3] = (dh3 + wc0) << 7;
    vo[4] = (dh0 + wc1) << 7;
    vo[5] = (dh1 + wc1) << 7;
    vo[6] = (dh2 + wc1) << 7;
    vo[7] = (dh3 + wc1) << 7;
    float bc0 = Bd0 * Ch0, bc1 = Bd0 * Ch1, bc2 = Bd1 * Ch0, bc3 = Bd1 * Ch1;
    wg[0] = bc0 * Aw0; wg[1] = bc1 * Aw0; wg[2] = bc2 * Aw0; wg[3] = bc3 * Aw0;
    wg[4] = bc0 * Aw1; wg[5] = bc1 * Aw1; wg[6] = bc2 * Aw1; wg[7] = bc3 * Aw1;
}

__global__ __launch_bounds__(64, 3) void deform_kernel(
    const unsigned short* __restrict__ xt, const float* __restrict__ off,
    const unsigned short* __restrict__ wt, float* __restrict__ part)
{
    const int lane = threadIdx.x;          // one wave per block
    const int n0   = lane & 15;            // my position within tile
    const int q    = lane >> 4;            // my channel chunk
    const int b    = blockIdx.x >> 9;      // 512 tiles per batch
    const int p0   = (blockIdx.x & 511) * TPW;
    const int kg   = blockIdx.y;           // 0..8

    const int pp = p0 + n0;
    const int ow = pp & 31;
    const int oh = (pp >> 5) & 31;
    const int od = pp >> 10;

    // byte base for my channel chunk: xt elem (b*PP + voxel)*64 + 8q -> bytes
    const char* xbq = (const char*)xt + (size_t)b * PP * 128 + q * 16;

    f32x4 acc[4];
    #pragma unroll
    for (int f = 0; f < 4; ++f) acc[f] = (f32x4)0.0f;

    int   vo[8], vo_n[8];
    float wg[8], wg_n[8];
    coords_k(off, b, kg * KPB, pp, ow, oh, od, vo, wg);

    #pragma unroll
    for (int kl = 0; kl < KPB; ++kl) {
        const int k = kg * KPB + kl;

        // ---- issue both gather batches (16 loads in flight)
        int4 va[8], vb[8];
        #pragma unroll
        for (int c = 0; c < 8; ++c) va[c] = *(const int4*)(xbq + vo[c]);
        #pragma unroll
        for (int c = 0; c < 8; ++c) vb[c] = *(const int4*)(xbq + vo[c] + 64);

        // ---- latency filler: next k's coords (off loads + ~60 VALU)
        if (kl + 1 < KPB)
            coords_k(off, b, k + 1, pp, ow, oh, od, vo_n, wg_n);

        // ---- consume gathers
        f32x2 s2[8];
        #pragma unroll
        for (int j = 0; j < 8; ++j) { s2[j].x = 0.0f; s2[j].y = 0.0f; }
        #pragma unroll
        for (int c = 0; c < 8; ++c) acc4pk(&s2[0], va[c], wg[c]);
        #pragma unroll
        for (int c = 0; c < 8; ++c) acc4pk(&s2[4], vb[c], wg[c]);

        // ---- weight A-frags (L2-hot; lifetime disjoint from va/vb)
        const unsigned short* wk = wt + k * (COUTC * CINC) + n0 * 64 + 8 * q;
        s16x8 wf0[4], wf1[4];
        #pragma unroll
        for (int f = 0; f < 4; ++f) {
            wf0[f] = *(const s16x8*)(wk + f * 1024);
            wf1[f] = *(const s16x8*)(wk + f * 1024 + 32);
        }

        // ---- pack to B-frags (already in MFMA B layout: k=8q+j, n=n0)
        s16x8 b0, b1;
        {
            int4 pk0, pk1;
            pk0.x = (int)pack2bf(s2[0].x, s2[0].y);
            pk0.y = (int)pack2bf(s2[1].x, s2[1].y);
            pk0.z = (int)pack2bf(s2[2].x, s2[2].y);
            pk0.w = (int)pack2bf(s2[3].x, s2[3].y);
            pk1.x = (int)pack2bf(s2[4].x, s2[4].y);
            pk1.y = (int)pack2bf(s2[5].x, s2[5].y);
            pk1.z = (int)pack2bf(s2[6].x, s2[6].y);
            pk1.w = (int)pack2bf(s2[7].x, s2[7].y);
            b0 = __builtin_bit_cast(s16x8, pk0);
            b1 = __builtin_bit_cast(s16x8, pk1);
        }

        #pragma unroll
        for (int f = 0; f < 4; ++f) {
            acc[f] = __builtin_amdgcn_mfma_f32_16x16x32_bf16(wf0[f], b0, acc[f], 0, 0, 0);
            acc[f] = __builtin_amdgcn_mfma_f32_16x16x32_bf16(wf1[f], b1, acc[f], 0, 0, 0);
        }

        if (kl + 1 < KPB) {
            #pragma unroll
            for (int j = 0; j < 8; ++j) { vo[j] = vo_n[j]; wg[j] = wg_n[j]; }
        }
    }

    // ---- epilogue: plain coalesced partial stores (no atomics, no bias here).
    // C/D layout: col=lane&15 -> p = pp ; row=4q+r -> o = 16f+4q+r
    float* pb = part + (size_t)(kg * BB + b) * (COUTC * PP);
    #pragma unroll
    for (int f = 0; f < 4; ++f) {
        #pragma unroll
        for (int r = 0; r < 4; ++r) {
            int o = 16 * f + 4 * q + r;
            pb[o * PP + pp] = acc[f][r];
        }
    }
}

// out[i] = bias + sum over 9 kg partials; fully coalesced float4 traffic.
__global__ __launch_bounds__(256) void reduce_kernel(
    const float4* __restrict__ part4, const float* __restrict__ bias,
    float4* __restrict__ out4)
{
    int i = blockIdx.x * 256 + threadIdx.x;      // 0..262143
    float bo = bias[(i >> 11) & 63];             // elem idx i*4 -> o = (i*4>>13)&63
    float4 s = make_float4(bo, bo, bo, bo);
    #pragma unroll
    for (int kg = 0; kg < KGRP; ++kg) {
        float4 v = part4[(size_t)kg * (OUTSZ / 4) + i];
        s.x += v.x; s.y += v.y; s.z += v.z; s.w += v.w;
    }
    out4[i] = s;
}

extern "C" void kernel_launch(void* const* d_in, const int* in_sizes, int n_in,
                              void* d_out, int out_size, void* d_ws, size_t ws_size,
                              hipStream_t stream) {
    const float* x    = (const float*)d_in[0];
    const float* off  = (const float*)d_in[1];
    const float* w    = (const float*)d_in[2];
    const float* bias = (const float*)d_in[3];
    float* out        = (float*)d_out;

    unsigned short* xt = (unsigned short*)d_ws;
    unsigned short* wt = (unsigned short*)((char*)d_ws + XT_BYTES);
    float* part        = (float*)((char*)d_ws + XT_BYTES + WT_BYTES);  // 9*4 MB partials

    hipLaunchKernelGGL(pre_kernel, dim3(256 + (KK * COUTC * CINC + 255) / 256), dim3(256), 0,
                       stream, x, w, xt, wt);
    hipLaunchKernelGGL(deform_kernel, dim3(BB * (PP / TPW), KGRP), dim3(64), 0, stream,
                       xt, off, wt, part);
    hipLaunchKernelGGL(reduce_kernel, dim3(OUTSZ / 4 / 256), dim3(256), 0, stream,
                       (const float4*)part, bias, (float4*)out);
}

// Round 9
// 104.585 us; speedup vs baseline: 2.2072x; 1.4677x over previous
//
#include <hip/hip_runtime.h>
#include <hip/hip_bf16.h>

// Deformable 3D conv: B=2, CIN=COUT=64, D=8,H=32,W=32, K=27, stride=1,pad=1,dil=1
// Round 9: explicit software pipeline, ZERO barriers. 256-thr blocks, wave-owned
// 16-position tiles: wave samples rows [16wv,16wv+16) of sS and MFMAs only those
// rows (same-wave DS ordering => no __syncthreads anywhere). Per k-step:
//   issue gathers(k) -> MFMA(k-1) -> coords(k+1)+off-prefetch(k+2) -> consume(k)
//   -> pack/ds_write -> load A-frags(k).
// A-frags come from wt2, a pre-laid per-lane fragment table (coalesced dwordx4).
// KGRP=3 (9 k/block), 768 blocks = 3/CU single generation. Partial stores+reduce.

#define BB    2
#define CINC  64
#define COUTC 64
#define DDEP  8
#define HGT   32
#define WID   32
#define KK    27
#define KGRP  3
#define KPB   9
#define PP    8192
#define LDW   72
#define OUTSZ (BB * COUTC * PP)
#define XT_BYTES  ((size_t)BB * PP * 64 * 2)        // 2097152
#define WT2_BYTES ((size_t)KK * 8 * 64 * 16)        // 221184

typedef short s16x8 __attribute__((ext_vector_type(8)));
typedef float f32x4 __attribute__((ext_vector_type(4)));
typedef float f32x2 __attribute__((ext_vector_type(2)));

__device__ __forceinline__ unsigned short f2bf(float f) {
    unsigned u = __builtin_bit_cast(unsigned, f);
    u += 0x7FFFu + ((u >> 16) & 1u);   // RNE
    return (unsigned short)(u >> 16);
}

__device__ __forceinline__ unsigned pack2bf(float lo, float hi) {
    return (unsigned)f2bf(lo) | ((unsigned)f2bf(hi) << 16);
}

__device__ __forceinline__ f32x2 bfu2(unsigned v) {
    f32x2 r;
    r.x = __builtin_bit_cast(float, v << 16);
    r.y = __builtin_bit_cast(float, v & 0xFFFF0000u);
    return r;
}

// Fused pre-kernel:
//  blocks [0,256): transpose+convert x[b][c][s] fp32 -> xt[b][s][c] bf16
//  blocks [256,310): weight -> wt2 per-lane A-fragment table:
//    block idx (k*8 + og*2 + j)*64 + lane holds 8 bf16: o=16og+(lane&15),
//    c=(lane>>4)*8 + 32j + i  (exact mfma_16x16x32 A layout)
__global__ void pre_kernel(const float* __restrict__ x, const float* __restrict__ w,
                           unsigned short* __restrict__ xt, unsigned short* __restrict__ wt2) {
    __shared__ float sT[64][65];
    const int t    = threadIdx.x;
    const int lane = t & 63;
    const int wv   = t >> 6;
    const int half = lane >> 5;
    const int c2   = lane & 31;
    int blk = blockIdx.x;
    if (blk < 256) {
        int b  = blk >> 7;
        int s0 = (blk & 127) * 64;
        #pragma unroll
        for (int i = 0; i < 16; ++i) {
            int c = wv * 16 + i;
            sT[c][lane] = x[(size_t)(b * CINC + c) * PP + s0 + lane];
        }
        __syncthreads();
        #pragma unroll
        for (int i = 0; i < 8; ++i) {
            int s = wv * 16 + 2 * i + half;
            unsigned pk = pack2bf(sT[2 * c2][s], sT[2 * c2 + 1][s]);
            *(unsigned*)&xt[(size_t)(b * PP + s0 + s) * 64 + 2 * c2] = pk;
        }
    } else {
        int id = (blk - 256) * 256 + t;       // 0..13823
        if (id < KK * 8 * 64) {
            int ln  = id & 63;
            int ogj = (id >> 6) & 7;
            int k   = id >> 9;
            int og  = ogj >> 1;
            int j   = ogj & 1;
            int o   = og * 16 + (ln & 15);
            int cb  = (ln >> 4) * 8 + 32 * j;
            unsigned short* dst = wt2 + (size_t)id * 8;
            #pragma unroll
            for (int i = 0; i < 8; ++i)
                dst[i] = f2bf(w[(size_t)(o * CINC + cb + i) * KK + k]);
        }
    }
}

__device__ __forceinline__ void acc4pk(f32x2* s2, int4 v, float wg) {
    f32x2 wg2; wg2.x = wg; wg2.y = wg;
    s2[0] += wg2 * bfu2((unsigned)v.x);
    s2[1] += wg2 * bfu2((unsigned)v.y);
    s2[2] += wg2 * bfu2((unsigned)v.z);
    s2[3] += wg2 * bfu2((unsigned)v.w);
}

// coords for tap k at my position from prefetched off values (validity folded)
__device__ __forceinline__ void coords_from(int k, int ow, int oh, int od,
                                            float o_d, float o_h, float o_w,
                                            int* __restrict__ vo, float* __restrict__ wg)
{
    const int kd = k / 9;
    const int kh = (k - kd * 9) / 3;
    const int kw = k - kd * 9 - kh * 3;
    float zd = (float)(od - 1 + kd) + o_d;
    float zh = (float)(oh - 1 + kh) + o_h;
    float zw = (float)(ow - 1 + kw) + o_w;

    float fdf = floorf(zd); int d0 = (int)fdf; float fd = zd - fdf;
    float fhf = floorf(zh); int h0 = (int)fhf; float fh = zh - fhf;
    float fwf = floorf(zw); int w0 = (int)fwf; float fw = zw - fwf;

    float Bd0 = (d0 >= 0     && d0 < DDEP)     ? 1.0f - fd : 0.0f;
    float Bd1 = (d0 + 1 >= 0 && d0 + 1 < DDEP) ? fd        : 0.0f;
    float Ch0 = (h0 >= 0     && h0 < HGT)      ? 1.0f - fh : 0.0f;
    float Ch1 = (h0 + 1 >= 0 && h0 + 1 < HGT)  ? fh        : 0.0f;
    float Aw0 = (w0 >= 0     && w0 < WID)      ? 1.0f - fw : 0.0f;
    float Aw1 = (w0 + 1 >= 0 && w0 + 1 < WID)  ? fw        : 0.0f;
    int dc0 = min(max(d0, 0), DDEP - 1);
    int dc1 = min(max(d0 + 1, 0), DDEP - 1);
    int hc0 = min(max(h0, 0), HGT - 1);
    int hc1 = min(max(h0 + 1, 0), HGT - 1);
    int wc0 = min(max(w0, 0), WID - 1);
    int wc1 = min(max(w0 + 1, 0), WID - 1);

    int dh0 = (dc0 * HGT + hc0) * WID;
    int dh1 = (dc0 * HGT + hc1) * WID;
    int dh2 = (dc1 * HGT + hc0) * WID;
    int dh3 = (dc1 * HGT + hc1) * WID;
    vo[0] = (dh0 + wc0) << 7;
    vo[1] = (dh1 + wc0) << 7;
    vo[2] = (dh2 + wc0) << 7;
    vo[3] = (dh3 + wc0) << 7;
    vo[4] = (dh0 + wc1) << 7;
    vo[5] = (dh1 + wc1) << 7;
    vo[6] = (dh2 + wc1) << 7;
    vo[7] = (dh3 + wc1) << 7;
    float bc0 = Bd0 * Ch0, bc1 = Bd0 * Ch1, bc2 = Bd1 * Ch0, bc3 = Bd1 * Ch1;
    wg[0] = bc0 * Aw0; wg[1] = bc1 * Aw0; wg[2] = bc2 * Aw0; wg[3] = bc3 * Aw0;
    wg[4] = bc0 * Aw1; wg[5] = bc1 * Aw1; wg[6] = bc2 * Aw1; wg[7] = bc3 * Aw1;
}

__global__ __launch_bounds__(256, 3) void deform_kernel(
    const unsigned short* __restrict__ xt, const float* __restrict__ off,
    const unsigned short* __restrict__ wt2, float* __restrict__ part)
{
    __shared__ unsigned short sS[64 * LDW] __attribute__((aligned(16)));  // 9216 B

    const int t    = threadIdx.x;
    const int lane = t & 63;
    const int wv   = t >> 6;
    const int n0   = lane & 15;
    const int q    = lane >> 4;
    const int b    = blockIdx.x >> 7;
    const int p0   = (blockIdx.x & 127) * 64;
    const int kg   = blockIdx.y;            // 0..2
    const int k0   = kg * KPB;

    // sampling role: 4 lanes per position, 16 positions per wave (wave-owned rows)
    const int sp  = wv * 16 + (lane >> 2);  // my sS row (position 0..63)
    const int cch = (lane & 3) * 16;        // byte offset of my channel chunk
    const int pp  = p0 + sp;
    const int ow  = pp & 31;
    const int oh  = (pp >> 5) & 31;
    const int od  = pp >> 10;

    const char*  xbq  = (const char*)xt + (size_t)b * PP * 128 + cch;
    const float* offb = off + (size_t)b * (3 * KK) * PP + pp;

    f32x4 acc[4];
    #pragma unroll
    for (int og = 0; og < 4; ++og) acc[og] = (f32x4)0.0f;

    int   vo[8], vo_n[8];
    float wg[8], wg_n[8];
    float of1_d, of1_h, of1_w;

    // ---- prologue: coords k0 (off latency exposed once), prefetch off k0+1
    {
        const float* ob = offb + (size_t)(3 * k0) * PP;
        float d = ob[0], h = ob[PP], w2 = ob[2 * PP];
        coords_from(k0, ow, oh, od, d, h, w2, vo, wg);
    }
    {
        const float* ob = offb + (size_t)(3 * (k0 + 1)) * PP;
        of1_d = ob[0]; of1_h = ob[PP]; of1_w = ob[2 * PP];
    }

    s16x8 wf[8];

    #pragma unroll
    for (int kl = 0; kl < KPB; ++kl) {
        const int k = k0 + kl;

        // ---- A: issue 16 gathers for k (8 corners x 2 half-lines)
        int4 va[8], vb[8];
        #pragma unroll
        for (int c = 0; c < 8; ++c) va[c] = *(const int4*)(xbq + vo[c]);
        #pragma unroll
        for (int c = 0; c < 8; ++c) vb[c] = *(const int4*)(xbq + vo[c] + 64);

        // ---- B: MFMA for k-1 (sS written last step by this wave; wf in regs)
        if (kl > 0) {
            s16x8 b0 = *(const s16x8*)&sS[(wv * 16 + n0) * LDW +      8 * q];
            s16x8 b1 = *(const s16x8*)&sS[(wv * 16 + n0) * LDW + 32 + 8 * q];
            #pragma unroll
            for (int og = 0; og < 4; ++og) {
                acc[og] = __builtin_amdgcn_mfma_f32_16x16x32_bf16(wf[2 * og],     b0, acc[og], 0, 0, 0);
                acc[og] = __builtin_amdgcn_mfma_f32_16x16x32_bf16(wf[2 * og + 1], b1, acc[og], 0, 0, 0);
            }
        }

        // ---- C: coords k+1 (off values prefetched) + issue off loads for k+2
        if (kl + 1 < KPB) {
            coords_from(k + 1, ow, oh, od, of1_d, of1_h, of1_w, vo_n, wg_n);
            if (kl + 2 < KPB) {
                const float* ob = offb + (size_t)(3 * (k + 2)) * PP;
                of1_d = ob[0]; of1_h = ob[PP]; of1_w = ob[2 * PP];
            }
        }

        // ---- E: consume gathers (16 channels: cch.. and 32+cch..)
        f32x2 slo[4], shi[4];
        #pragma unroll
        for (int j = 0; j < 4; ++j) { slo[j].x = 0; slo[j].y = 0; shi[j].x = 0; shi[j].y = 0; }
        #pragma unroll
        for (int c = 0; c < 8; ++c) acc4pk(slo, va[c], wg[c]);
        #pragma unroll
        for (int c = 0; c < 8; ++c) acc4pk(shi, vb[c], wg[c]);

        // ---- F: pack + same-wave LDS write (no barrier: DS in-order per wave)
        {
            int4 pk0, pk1;
            pk0.x = (int)pack2bf(slo[0].x, slo[0].y);
            pk0.y = (int)pack2bf(slo[1].x, slo[1].y);
            pk0.z = (int)pack2bf(slo[2].x, slo[2].y);
            pk0.w = (int)pack2bf(slo[3].x, slo[3].y);
            pk1.x = (int)pack2bf(shi[0].x, shi[0].y);
            pk1.y = (int)pack2bf(shi[1].x, shi[1].y);
            pk1.z = (int)pack2bf(shi[2].x, shi[2].y);
            pk1.w = (int)pack2bf(shi[3].x, shi[3].y);
            *(int4*)&sS[sp * LDW +      8 * (lane & 3)] = pk0;
            *(int4*)&sS[sp * LDW + 32 + 8 * (lane & 3)] = pk1;
        }

        // ---- D: A-frags for THIS k (consumed by next step's MFMA); coalesced
        {
            const unsigned short* wk = wt2 + ((size_t)k * 512 + lane) * 8;
            #pragma unroll
            for (int fj = 0; fj < 8; ++fj)
                wf[fj] = *(const s16x8*)(wk + (size_t)fj * 512);
        }

        // ---- rotate coords
        if (kl + 1 < KPB) {
            #pragma unroll
            for (int j = 0; j < 8; ++j) { vo[j] = vo_n[j]; wg[j] = wg_n[j]; }
        }
    }

    // ---- tail MFMA for k = k0+8
    {
        s16x8 b0 = *(const s16x8*)&sS[(wv * 16 + n0) * LDW +      8 * q];
        s16x8 b1 = *(const s16x8*)&sS[(wv * 16 + n0) * LDW + 32 + 8 * q];
        #pragma unroll
        for (int og = 0; og < 4; ++og) {
            acc[og] = __builtin_amdgcn_mfma_f32_16x16x32_bf16(wf[2 * og],     b0, acc[og], 0, 0, 0);
            acc[og] = __builtin_amdgcn_mfma_f32_16x16x32_bf16(wf[2 * og + 1], b1, acc[og], 0, 0, 0);
        }
    }

    // ---- epilogue: plain coalesced partial stores.
    // C/D: col=lane&15 -> p = p0+16wv+n0 ; row=4q+r -> o = 16og+4q+r
    float* pb = part + (size_t)(kg * BB + b) * (COUTC * PP);
    const int pdst = p0 + 16 * wv + n0;
    #pragma unroll
    for (int og = 0; og < 4; ++og) {
        #pragma unroll
        for (int r = 0; r < 4; ++r) {
            pb[(16 * og + 4 * q + r) * PP + pdst] = acc[og][r];
        }
    }
}

// out = bias + sum of 3 kg partials; fully coalesced float4 traffic.
__global__ __launch_bounds__(256) void reduce_kernel(
    const float4* __restrict__ part4, const float* __restrict__ bias,
    float4* __restrict__ out4)
{
    int i = blockIdx.x * 256 + threadIdx.x;      // 0..262143
    float bo = bias[(i >> 11) & 63];
    float4 s = make_float4(bo, bo, bo, bo);
    #pragma unroll
    for (int g = 0; g < KGRP; ++g) {
        float4 v = part4[(size_t)g * (OUTSZ / 4) + i];
        s.x += v.x; s.y += v.y; s.z += v.z; s.w += v.w;
    }
    out4[i] = s;
}

extern "C" void kernel_launch(void* const* d_in, const int* in_sizes, int n_in,
                              void* d_out, int out_size, void* d_ws, size_t ws_size,
                              hipStream_t stream) {
    const float* x    = (const float*)d_in[0];
    const float* off  = (const float*)d_in[1];
    const float* w    = (const float*)d_in[2];
    const float* bias = (const float*)d_in[3];
    float* out        = (float*)d_out;

    unsigned short* xt  = (unsigned short*)d_ws;
    unsigned short* wt2 = (unsigned short*)((char*)d_ws + XT_BYTES);
    float* part         = (float*)((char*)d_ws + XT_BYTES + WT2_BYTES);  // 3*4 MB

    hipLaunchKernelGGL(pre_kernel, dim3(256 + 54), dim3(256), 0, stream, x, w, xt, wt2);
    hipLaunchKernelGGL(deform_kernel, dim3(BB * (PP / 64), KGRP), dim3(256), 0, stream,
                       xt, off, wt2, part);
    hipLaunchKernelGGL(reduce_kernel, dim3(OUTSZ / 4 / 256), dim3(256), 0, stream,
                       (const float4*)part, bias, (float4*)out);
}